// Round 3
// baseline (111.725 us; speedup 1.0000x reference)
//
#include <hip/hip_runtime.h>
#include <stdint.h>

#define B_DIM 16384
#define T_DIM 128
// one block = 256 threads, 4 elements/thread = 1024 elements = 8 batches
#define BATCHES_PER_BLOCK 8
#define NBLOCKS (B_DIM / BATCHES_PER_BLOCK)   // 2048

struct U2 { uint32_t a, b; };

__host__ __device__ constexpr uint32_t rotl32c(uint32_t x, uint32_t n) {
    return (x << n) | (x >> (32u - n));
}

// JAX threefry2x32 block cipher (20 rounds), bit-exact.
__host__ __device__ constexpr U2 tf(uint32_t k0, uint32_t k1,
                                    uint32_t x0, uint32_t x1) {
    uint32_t ks2 = k0 ^ k1 ^ 0x1BD11BDAu;
    x0 += k0; x1 += k1;
#define RND(r) { x0 += x1; x1 = rotl32c(x1, r); x1 ^= x0; }
    RND(13) RND(15) RND(26) RND(6)
    x0 += k1; x1 += ks2 + 1u;
    RND(17) RND(29) RND(16) RND(24)
    x0 += ks2; x1 += k0 + 2u;
    RND(13) RND(15) RND(26) RND(6)
    x0 += k0; x1 += k1 + 3u;
    RND(17) RND(29) RND(16) RND(24)
    x0 += k1; x1 += ks2 + 4u;
    RND(13) RND(15) RND(26) RND(6)
    x0 += ks2; x1 += k0 + 5u;
#undef RND
    return U2{x0, x1};
}

// jax_threefry_partitionable=True: split child i = tf(key; 0, i) (full output);
// random_bits(key,32,(N,)): bits[i] = o0 ^ o1 of tf(key; 0, i).
// key(42) = (0,42); key,sub = split(key) -> sub = tf(key;0,1); k0..k3 = split(sub,4).
constexpr U2 SUB = tf(0u, 42u, 0u, 1u);
constexpr U2 K0 = tf(SUB.a, SUB.b, 0u, 0u);  // ax
constexpr U2 K1 = tf(SUB.a, SUB.b, 0u, 1u);  // ay
constexpr U2 K2 = tf(SUB.a, SUB.b, 0u, 2u);  // az
constexpr U2 K3 = tf(SUB.a, SUB.b, 0u, 3u);  // mask

__device__ __forceinline__ float bits_to_uniform(uint32_t bits) {
    uint32_t u = (bits >> 9) | 0x3F800000u;
    return __uint_as_float(u) - 1.0f;
}

__device__ __forceinline__ uint32_t rbits(U2 k, uint32_t i) {
    U2 o = tf(k.a, k.b, 0u, i);
    return o.a ^ o.b;
}

__device__ __forceinline__ void mat_to_quat_xyzw(
    float n00, float n01, float n02,
    float n10, float n11, float n12,
    float n20, float n21, float n22,
    float4& qo) {
    float t0 = 1.0f + n00 + n11 + n22;
    float t1 = 1.0f + n00 - n11 - n22;
    float t2 = 1.0f - n00 + n11 - n22;
    float t3 = 1.0f - n00 - n11 + n22;
    float q0 = sqrtf(fmaxf(t0, 1e-8f));
    float q1 = sqrtf(fmaxf(t1, 1e-8f));
    float q2 = sqrtf(fmaxf(t2, 1e-8f));
    float q3 = sqrtf(fmaxf(t3, 1e-8f));

    int best = 0; float bv = q0;          // jnp.argmax: first max wins
    if (q1 > bv) { best = 1; bv = q1; }
    if (q2 > bv) { best = 2; bv = q2; }
    if (q3 > bv) { best = 3; bv = q3; }
    float inv = 1.0f / (2.0f * fmaxf(bv, 0.1f));

    float w, x, y, z;
    if (best == 0)      { w = q0 * q0;  x = n21 - n12; y = n02 - n20; z = n10 - n01; }
    else if (best == 1) { w = n21 - n12; x = q1 * q1;  y = n01 + n10; z = n02 + n20; }
    else if (best == 2) { w = n02 - n20; x = n10 + n01; y = q2 * q2;  z = n12 + n21; }
    else                { w = n10 - n01; x = n20 + n02; y = n21 + n12; z = q3 * q3;  }

    qo.x = x * inv; qo.y = y * inv; qo.z = z * inv; qo.w = w * inv;
}

__global__ __launch_bounds__(256) void rot_fused_kernel(
    const float* __restrict__ pos, const float* __restrict__ quat,
    float* __restrict__ pos_out, float* __restrict__ quat_out,
    float* __restrict__ Rf) {
    __shared__ float Rs[BATCHES_PER_BLOCK][12];   // 9 used, pad to 12

    int t = threadIdx.x;
    int blk = blockIdx.x;
    size_t e0 = ((size_t)blk * 256 + t) * 4;      // first of 4 elements

    // Issue all global loads up front (overlap with R computation below).
    const float4* p4 = (const float4*)(pos + e0 * 3);
    float4 pA = p4[0], pB = p4[1], pC = p4[2];
    const float4* q4 = (const float4*)(quat + e0 * 4);
    float4 qA = q4[0], qB = q4[1], qC = q4[2], qD = q4[3];

    // Threads 0..7 build R for the block's 8 batches.
    if (t < BATCHES_PER_BLOCK) {
        uint32_t b = (uint32_t)(blk * BATCHES_PER_BLOCK + t);
        uint32_t bx = rbits(K0, b);
        uint32_t by = rbits(K1, b);
        uint32_t bz = rbits(K2, b);
        uint32_t bm = rbits(K3, b);

        const float PI_F = 3.14159265358979323846f;
        float ax = bits_to_uniform(bx) * 2.0f * PI_F - PI_F;
        float ay = bits_to_uniform(by) * 2.0f * PI_F - PI_F;
        float az = bits_to_uniform(bz) * 2.0f * PI_F - PI_F;
        if (bits_to_uniform(bm) < 0.015625f) { ax = 0.0f; ay = 0.0f; az = 0.0f; }

        float sx, cx, sy, cy, sz, cz;
        sincosf(ax, &sx, &cx);
        sincosf(ay, &sy, &cy);
        sincosf(az, &sz, &cz);

        Rs[t][0] = cz * cy;
        Rs[t][1] = cz * sy * sx - sz * cx;
        Rs[t][2] = cz * sy * cx + sz * sx;
        Rs[t][3] = sz * cy;
        Rs[t][4] = sz * sy * sx + cz * cx;
        Rs[t][5] = sz * sy * cx - cz * sx;
        Rs[t][6] = -sy;
        Rs[t][7] = cy * sx;
        Rs[t][8] = cy * cx;
    }
    __syncthreads();

    // Rf output slice, coalesced: 72 floats per block.
    if (t < 9 * BATCHES_PER_BLOCK) {
        Rf[(size_t)blk * 72 + t] = Rs[t / 9][t % 9];
    }

    // Broadcast R for this thread's batch (wave-uniform per 32-lane group).
    int rb = t >> 5;
    float R00 = Rs[rb][0], R01 = Rs[rb][1], R02 = Rs[rb][2];
    float R10 = Rs[rb][3], R11 = Rs[rb][4], R12 = Rs[rb][5];
    float R20 = Rs[rb][6], R21 = Rs[rb][7], R22 = Rs[rb][8];

    // Unpack 4 pos elements from 3 float4s.
    float px[4] = { pA.x, pA.w, pB.z, pC.y };
    float py[4] = { pA.y, pB.x, pB.w, pC.z };
    float pz[4] = { pA.z, pB.y, pC.x, pC.w };
    float ox[4], oy[4], oz[4];
#pragma unroll
    for (int i = 0; i < 4; ++i) {
        ox[i] = R00 * px[i] + R01 * py[i] + R02 * pz[i];
        oy[i] = R10 * px[i] + R11 * py[i] + R12 * pz[i];
        oz[i] = R20 * px[i] + R21 * py[i] + R22 * pz[i];
    }
    float4* po4 = (float4*)(pos_out + e0 * 3);
    po4[0] = make_float4(ox[0], oy[0], oz[0], ox[1]);
    po4[1] = make_float4(oy[1], oz[1], ox[2], oy[2]);
    po4[2] = make_float4(oz[2], ox[3], oy[3], oz[3]);

    // Quats: 4 elements.
    float4 qin[4] = { qA, qB, qC, qD };
    float4 qout[4];
#pragma unroll
    for (int i = 0; i < 4; ++i) {
        float qx = qin[i].x, qy = qin[i].y, qz = qin[i].z, qw = qin[i].w;
        float ss = qw * qw + qx * qx + qy * qy + qz * qz;
        float two = 2.0f / ss;
        float m00 = 1.0f - two * (qy * qy + qz * qz);
        float m01 = two * (qx * qy - qz * qw);
        float m02 = two * (qx * qz + qy * qw);
        float m10 = two * (qx * qy + qz * qw);
        float m11 = 1.0f - two * (qx * qx + qz * qz);
        float m12 = two * (qy * qz - qx * qw);
        float m20 = two * (qx * qz - qy * qw);
        float m21 = two * (qy * qz + qx * qw);
        float m22 = 1.0f - two * (qx * qx + qy * qy);

        float n00 = R00 * m00 + R01 * m10 + R02 * m20;
        float n01 = R00 * m01 + R01 * m11 + R02 * m21;
        float n02 = R00 * m02 + R01 * m12 + R02 * m22;
        float n10 = R10 * m00 + R11 * m10 + R12 * m20;
        float n11 = R10 * m01 + R11 * m11 + R12 * m21;
        float n12 = R10 * m02 + R11 * m12 + R12 * m22;
        float n20 = R20 * m00 + R21 * m10 + R22 * m20;
        float n21 = R20 * m01 + R21 * m11 + R22 * m21;
        float n22 = R20 * m02 + R21 * m12 + R22 * m22;

        mat_to_quat_xyzw(n00, n01, n02, n10, n11, n12, n20, n21, n22, qout[i]);
    }
    float4* qo4 = (float4*)(quat_out + e0 * 4);
    qo4[0] = qout[0]; qo4[1] = qout[1]; qo4[2] = qout[2]; qo4[3] = qout[3];
}

extern "C" void kernel_launch(void* const* d_in, const int* in_sizes, int n_in,
                              void* d_out, int out_size, void* d_ws, size_t ws_size,
                              hipStream_t stream) {
    const float* pos  = (const float*)d_in[0];
    const float* quat = (const float*)d_in[1];
    float* out = (float*)d_out;
    float* pos_out  = out;                                   // B*T*3
    float* quat_out = out + (size_t)B_DIM * T_DIM * 3;       // B*T*4
    float* Rf       = out + (size_t)B_DIM * T_DIM * 7;       // B*9

    rot_fused_kernel<<<NBLOCKS, 256, 0, stream>>>(pos, quat, pos_out, quat_out, Rf);
}